// Round 11
// baseline (148.555 us; speedup 1.0000x reference)
//
#include <hip/hip_runtime.h>
#include <hip/hip_fp16.h>

typedef _Float16 half8 __attribute__((ext_vector_type(8)));
typedef float f32x4 __attribute__((ext_vector_type(4)));

#define BHSZ 16777216  // 65536 * 256
#define SBAR() __builtin_amdgcn_s_barrier()

__device__ __forceinline__ void gload16(const void* g, const void* lds) {
  __builtin_amdgcn_global_load_lds((const __attribute__((address_space(1))) void*)g,
                                   (__attribute__((address_space(3))) void*)lds,
                                   16, 0, 0);
}

__device__ __forceinline__ float fast_sigmoid(float z) {
  float e = __builtin_amdgcn_exp2f(-z * 1.4426950408889634f);
  return __builtin_amdgcn_rcpf(1.0f + e);
}

__device__ __forceinline__ float fast_tanh(float z) {
  float a = __builtin_fabsf(z);
  float e = __builtin_amdgcn_exp2f(a * 2.8853900817779268f);
  float t = 1.0f - 2.0f * __builtin_amdgcn_rcpf(1.0f + e);
  return z < 0.0f ? -t : t;
}

// ---------------------------------------------------------------------------
// pack_a: Apk[b][k] fp16, k<256 -> x[b][k], k>=256 -> h[b][k-256]  (r1-verbatim)
// ---------------------------------------------------------------------------
__global__ __launch_bounds__(256) void pack_a(const float* __restrict__ x,
                                              const float* __restrict__ h,
                                              _Float16* __restrict__ Apk) {
  long i = (long)blockIdx.x * 256 + threadIdx.x;
  long e = i * 8;
  int b = (int)(e >> 9);
  int k = (int)(e & 511);
  const float* src = (k < 256) ? (x + (long)b * 256 + k)
                               : (h + (long)b * 256 + (k - 256));
  float4 v0 = reinterpret_cast<const float4*>(src)[0];
  float4 v1 = reinterpret_cast<const float4*>(src)[1];
  half8 o;
  o[0] = (_Float16)v0.x; o[1] = (_Float16)v0.y;
  o[2] = (_Float16)v0.z; o[3] = (_Float16)v0.w;
  o[4] = (_Float16)v1.x; o[5] = (_Float16)v1.y;
  o[6] = (_Float16)v1.z; o[7] = (_Float16)v1.w;
  *reinterpret_cast<half8*>(Apk + e) = o;
}

// ---------------------------------------------------------------------------
// pack_b: Bp[N'][k] fp16 (B^T, N'-major), gate-interleaved columns:
//   N' = t*64 + g*16 + j -> logical col cl = t*16 + j, gate g (0=f,1=i,2=o,3=c)
// ---------------------------------------------------------------------------
__global__ __launch_bounds__(256) void pack_b(
    const float* __restrict__ Wf, const float* __restrict__ Uf,
    const float* __restrict__ Wi, const float* __restrict__ Ui,
    const float* __restrict__ Wo, const float* __restrict__ Uo,
    const float* __restrict__ Wc, const float* __restrict__ Uc,
    _Float16* __restrict__ Bp) {
  int idx = blockIdx.x * 256 + threadIdx.x;  // [0, 524288)
  int k = idx & 511;
  int Np = idx >> 9;
  int g = (Np >> 4) & 3;
  int cl = ((Np >> 6) << 4) | (Np & 15);
  const float* W;
  const float* U;
  switch (g) {
    case 0: W = Wf; U = Uf; break;
    case 1: W = Wi; U = Ui; break;
    case 2: W = Wo; U = Uo; break;
    default: W = Wc; U = Uc; break;
  }
  float v = (k < 256) ? W[k * 256 + cl] : U[(k - 256) * 256 + cl];
  Bp[idx] = (_Float16)v;
}

// ---------------------------------------------------------------------------
// lstm_gemm: 256x256 tile, 512 thr (8 waves 2Mx4N; wave 128x64, acc 8x4).
// m201-faithful counted-vmcnt schedule, phase = 32-k half-tile (16 phases):
//   LDS ring-4 of 32KB slots: [A 256x32 fp16 | B 256x32 fp16], rowpair-line
//   format (128B line, 8 chunks, chunk = ((r&1)*4+kc)^(rp&7)) -- r8-verified
//   zero-conflict for both gload_lds dests and fragment reads.
//   Prologue stages slots 0..2 (4 loads/thread each). Phase j:
//     s_waitcnt vmcnt(8)   (drains slot j only; j+1,j+2 stay in flight)
//     s_barrier
//     stage slot j+3       (writes slot (j-1)&3: readers passed the barrier)
//     12x ds_read_b128 + 32 MFMA (setprio-wrapped)
//   vmcnt -> 4 at j=14, 0 at j=15 only. ~3-phase (~800cy) load lead.
// grid = 1024 (256 bm x 4 bn); XCD-grouped, bn-fastest (A-panel L2 share).
// ---------------------------------------------------------------------------
__global__ __launch_bounds__(512, 2) void lstm_gemm(
    const _Float16* __restrict__ Apk, const _Float16* __restrict__ Bp,
    const float* __restrict__ cin,
    const float* __restrict__ bf_, const float* __restrict__ bi_,
    const float* __restrict__ bo_, const float* __restrict__ bc_,
    float* __restrict__ out) {
  __shared__ __align__(16) char smem[131072];  // 4 slots x 32KB

  int tid = threadIdx.x;
  int w = tid >> 6, l = tid & 63;
  int l15 = l & 15, lg = l >> 4;
  int wr = w >> 2, wcn = w & 3;

  int bid = blockIdx.x;
  int wg = (bid & 7) * 128 + (bid >> 3);
  int bm = wg >> 2, bn = wg & 3;

  // --- staging source map (r10-verbatim): dest chunk tid covers one 16B
  // chunk of an 8KB (128-row x 32-k) stage unit. rp=tid>>3, s8=tid&7,
  // i8=s8^(rp&7); source row = 2*rp + (i8>>2) (+hf*128), k-off = (i8&3)*8.
  int rpl = tid >> 3, s8 = tid & 7;
  int i8 = s8 ^ (rpl & 7);
  int rbase = 2 * rpl + (i8 >> 2);  // 0..127
  int csrc = (i8 & 3) * 8;
  long sA = ((long)bm * 256 + rbase) * 512 + csrc;
  long sB = ((long)bn * 256 + rbase) * 512 + csrc;
  int wb1k = w * 1024;  // wave-uniform LDS dest base (HW adds lane*16)

  // --- fragment read byte-offsets within a slot ---
  int offA[8], offB[4];
#pragma unroll
  for (int mf = 0; mf < 8; ++mf) {
    int r = wr * 128 + mf * 16 + l15;
    int rp = r >> 1;
    offA[mf] = rp * 128 + (((((r & 1) << 2) | lg) ^ (rp & 7)) << 4);
  }
#pragma unroll
  for (int nf = 0; nf < 4; ++nf) {
    int r = wcn * 64 + nf * 16 + l15;
    int rp = r >> 1;
    offB[nf] = 16384 + rp * 128 + (((((r & 1) << 2) | lg) ^ (rp & 7)) << 4);
  }

  f32x4 acc[8][4];
#pragma unroll
  for (int a2 = 0; a2 < 8; ++a2)
#pragma unroll
    for (int b2 = 0; b2 < 4; ++b2)
      acc[a2][b2] = (f32x4){0.f, 0.f, 0.f, 0.f};

  // stage slot for k-half js (0..15): 4 gload16/thread (A hf0, A hf1, B hf0,
  // B hf1), each filling an 8KB unit of slot js&3.
  auto stage = [&](int js) {
    char* db = smem + (js & 3) * 32768;
    long ko = (long)js * 32;
#pragma unroll
    for (int hf = 0; hf < 2; ++hf)
      gload16(Apk + sA + ko + (long)hf * 128 * 512, db + hf * 8192 + wb1k);
#pragma unroll
    for (int hf = 0; hf < 2; ++hf)
      gload16(Bp + sB + ko + (long)hf * 128 * 512,
              db + 16384 + hf * 8192 + wb1k);
  };

  // --- Prologue: slots 0,1,2 in flight (12 loads/thread).
  stage(0);
  stage(1);
  stage(2);

#pragma unroll
  for (int j = 0; j < 16; ++j) {
    if (j <= 13)
      asm volatile("s_waitcnt vmcnt(8)" ::: "memory");
    else if (j == 14)
      asm volatile("s_waitcnt vmcnt(4)" ::: "memory");
    else
      asm volatile("s_waitcnt vmcnt(0)" ::: "memory");
    SBAR();
    if (j <= 12) stage(j + 3);

    const char* sb = smem + (j & 3) * 32768;
    half8 bv[4], av[8];
#pragma unroll
    for (int nf = 0; nf < 4; ++nf)
      bv[nf] = *reinterpret_cast<const half8*>(sb + offB[nf]);
#pragma unroll
    for (int mf = 0; mf < 8; ++mf)
      av[mf] = *reinterpret_cast<const half8*>(sb + offA[mf]);
    __builtin_amdgcn_s_setprio(1);
#pragma unroll
    for (int mf = 0; mf < 8; ++mf)
#pragma unroll
      for (int nf = 0; nf < 4; ++nf)
        acc[mf][nf] = __builtin_amdgcn_mfma_f32_16x16x32_f16(
            av[mf], bv[nf], acc[mf][nf], 0, 0, 0);
    __builtin_amdgcn_s_setprio(0);
  }

  // --- Epilogue: n-frag == gate (0=f,1=i,2=o,3=c); C/D: col=lane&15,
  // row=(lane>>4)*4+reg.
  int col = (bn * 4 + wcn) * 16 + l15;  // logical column in [0,256)
  float vbf = bf_[col], vbi = bi_[col], vbo = bo_[col], vbc = bc_[col];
#pragma unroll
  for (int mf = 0; mf < 8; ++mf) {
#pragma unroll
    for (int r = 0; r < 4; ++r) {
      long row = (long)(bm * 256 + wr * 128 + mf * 16 + lg * 4 + r);
      float zf = acc[mf][0][r] + vbf;
      float zi = acc[mf][1][r] + vbi;
      float zo = acc[mf][2][r] + vbo;
      float zg = acc[mf][3][r] + vbc;
      float fg = fast_sigmoid(zf);
      float ig = fast_sigmoid(zi);
      float og = fast_sigmoid(zo);
      float gg = fast_tanh(zg);
      float cv = cin[row * 256 + col];
      float cn = cv * fg + gg * ig;
      float hn = og * fast_tanh(cn);
      out[row * 256 + col] = cn;
      out[BHSZ + row * 256 + col] = hn;
    }
  }
}

// ---------------------------------------------------------------------------
extern "C" void kernel_launch(void* const* d_in, const int* in_sizes, int n_in,
                              void* d_out, int out_size, void* d_ws, size_t ws_size,
                              hipStream_t stream) {
  const float* x  = (const float*)d_in[0];
  const float* c  = (const float*)d_in[1];
  const float* h  = (const float*)d_in[2];
  const float* Wi = (const float*)d_in[3];
  const float* Ui = (const float*)d_in[4];
  const float* bi = (const float*)d_in[5];
  const float* Wf = (const float*)d_in[6];
  const float* Uf = (const float*)d_in[7];
  const float* bf = (const float*)d_in[8];
  const float* Wc = (const float*)d_in[9];
  const float* Uc = (const float*)d_in[10];
  const float* bc = (const float*)d_in[11];
  const float* Wo = (const float*)d_in[12];
  const float* Uo = (const float*)d_in[13];
  const float* bo = (const float*)d_in[14];

  _Float16* Apk = (_Float16*)d_ws;                                    // 64 MB
  _Float16* Bp  = (_Float16*)((char*)d_ws + (size_t)65536 * 512 * 2); // 1 MB

  pack_a<<<16384, 256, 0, stream>>>(x, h, Apk);
  pack_b<<<2048, 256, 0, stream>>>(Wf, Uf, Wi, Ui, Wo, Uo, Wc, Uc, Bp);
  lstm_gemm<<<1024, 512, 0, stream>>>(Apk, Bp, c, bf, bi, bo, bc,
                                      (float*)d_out);
}

// Round 12
// 146.240 us; speedup vs baseline: 1.0158x; 1.0158x over previous
//
#include <hip/hip_runtime.h>
#include <hip/hip_fp16.h>

typedef _Float16 half8 __attribute__((ext_vector_type(8)));
typedef float f32x4 __attribute__((ext_vector_type(4)));

#define BHSZ 16777216  // 65536 * 256
#define SBAR() __builtin_amdgcn_s_barrier()

__device__ __forceinline__ void gload16(const void* g, const void* lds) {
  __builtin_amdgcn_global_load_lds((const __attribute__((address_space(1))) void*)g,
                                   (__attribute__((address_space(3))) void*)lds,
                                   16, 0, 0);
}

__device__ __forceinline__ float fast_sigmoid(float z) {
  float e = __builtin_amdgcn_exp2f(-z * 1.4426950408889634f);
  return __builtin_amdgcn_rcpf(1.0f + e);
}

__device__ __forceinline__ float fast_tanh(float z) {
  float a = __builtin_fabsf(z);
  float e = __builtin_amdgcn_exp2f(a * 2.8853900817779268f);
  float t = 1.0f - 2.0f * __builtin_amdgcn_rcpf(1.0f + e);
  return z < 0.0f ? -t : t;
}

// ---------------------------------------------------------------------------
// pack_a: Apk[b][k] fp16, k<256 -> x[b][k], k>=256 -> h[b][k-256]
// ---------------------------------------------------------------------------
__global__ __launch_bounds__(256) void pack_a(const float* __restrict__ x,
                                              const float* __restrict__ h,
                                              _Float16* __restrict__ Apk) {
  long i = (long)blockIdx.x * 256 + threadIdx.x;
  long e = i * 8;
  int b = (int)(e >> 9);
  int k = (int)(e & 511);
  const float* src = (k < 256) ? (x + (long)b * 256 + k)
                               : (h + (long)b * 256 + (k - 256));
  float4 v0 = reinterpret_cast<const float4*>(src)[0];
  float4 v1 = reinterpret_cast<const float4*>(src)[1];
  half8 o;
  o[0] = (_Float16)v0.x; o[1] = (_Float16)v0.y;
  o[2] = (_Float16)v0.z; o[3] = (_Float16)v0.w;
  o[4] = (_Float16)v1.x; o[5] = (_Float16)v1.y;
  o[6] = (_Float16)v1.z; o[7] = (_Float16)v1.w;
  *reinterpret_cast<half8*>(Apk + e) = o;
}

// ---------------------------------------------------------------------------
// pack_b: Bp[N'][k] fp16 (B^T, N'-major), gate-interleaved columns:
//   N' = t*64 + g*16 + j -> logical col cl = t*16 + j, gate g (0=f,1=i,2=o,3=c)
// ---------------------------------------------------------------------------
__global__ __launch_bounds__(256) void pack_b(
    const float* __restrict__ Wf, const float* __restrict__ Uf,
    const float* __restrict__ Wi, const float* __restrict__ Ui,
    const float* __restrict__ Wo, const float* __restrict__ Uo,
    const float* __restrict__ Wc, const float* __restrict__ Uc,
    _Float16* __restrict__ Bp) {
  int idx = blockIdx.x * 256 + threadIdx.x;  // [0, 524288)
  int k = idx & 511;
  int Np = idx >> 9;
  int g = (Np >> 4) & 3;
  int cl = ((Np >> 6) << 4) | (Np & 15);
  const float* W;
  const float* U;
  switch (g) {
    case 0: W = Wf; U = Uf; break;
    case 1: W = Wi; U = Ui; break;
    case 2: W = Wo; U = Uo; break;
    default: W = Wc; U = Uc; break;
  }
  float v = (k < 256) ? W[k * 256 + cl] : U[(k - 256) * 256 + cl];
  Bp[idx] = (_Float16)v;
}

// ---------------------------------------------------------------------------
// lstm_gemm: 256(M) x 128(N') tile, 512 thr (8 waves 4Mx2N; wave 64x64,
// acc 4x4 f32x4 = 64 -> VGPR ~120 -> 4 waves/SIMD). LDS ring-3 of 24KB
// slots (A 256x32 fp16 16K + B 128x32 fp16 8K), rowpair-line zero-conflict
// layout (r8-verified). 72KB LDS + <=128 VGPR -> TWO blocks/CU: phase-
// shifted blocks hide each other's barrier drains and trans-heavy epilogue.
// Phase j (16 phases of k=32): vmcnt(3) [slot j done; j+1 in flight],
// s_barrier, stage slot j+2 (3 gload_lds/thread), 8x ds_read_b128 + 16 MFMA
// (setprio). vmcnt(0) only at j=15.
// grid = 2048 (256 bm x 8 bn); XCD-grouped, bn-fastest (A-panel L2 share).
// ---------------------------------------------------------------------------
__global__ __launch_bounds__(512, 4) void lstm_gemm(
    const _Float16* __restrict__ Apk, const _Float16* __restrict__ Bp,
    const float* __restrict__ cin,
    const float* __restrict__ bf_, const float* __restrict__ bi_,
    const float* __restrict__ bo_, const float* __restrict__ bc_,
    float* __restrict__ out) {
  __shared__ __align__(16) char smem[73728];  // 3 slots x 24KB

  int tid = threadIdx.x;
  int w = tid >> 6, l = tid & 63;
  int l15 = l & 15, lg = l >> 4;
  int wr = w >> 1, wcn = w & 1;

  int bid = blockIdx.x;
  int wg = (bid & 7) * 256 + (bid >> 3);
  int bm = wg >> 3, bn = wg & 7;

  // --- staging source map: dest chunk tid covers one 16B chunk of an 8KB
  // (128-row x 32-k) stage unit. rp=tid>>3, s8=tid&7, i8=s8^(rp&7);
  // source row = 2*rp + (i8>>2), k-off = (i8&3)*8.
  int rpl = tid >> 3, s8 = tid & 7;
  int i8 = s8 ^ (rpl & 7);
  int rbase = 2 * rpl + (i8 >> 2);  // 0..127
  int csrc = (i8 & 3) * 8;
  long sA = ((long)bm * 256 + rbase) * 512 + csrc;  // + p*128 rows for unit p
  long sB = ((long)bn * 128 + rbase) * 512 + csrc;
  int wb1k = w * 1024;  // wave-uniform LDS dest base (HW adds lane*16)

  // --- fragment read byte-offsets within a slot ---
  int offA[4], offB[4];
#pragma unroll
  for (int mf = 0; mf < 4; ++mf) {
    int r = wr * 64 + mf * 16 + l15;  // 0..255
    int rp = r >> 1;
    offA[mf] = rp * 128 + (((((r & 1) << 2) | lg) ^ (rp & 7)) << 4);
  }
#pragma unroll
  for (int nf = 0; nf < 4; ++nf) {
    int r = wcn * 64 + nf * 16 + l15;  // 0..127
    int rp = r >> 1;
    offB[nf] = 16384 + rp * 128 + (((((r & 1) << 2) | lg) ^ (rp & 7)) << 4);
  }

  f32x4 acc[4][4];
#pragma unroll
  for (int a2 = 0; a2 < 4; ++a2)
#pragma unroll
    for (int b2 = 0; b2 < 4; ++b2)
      acc[a2][b2] = (f32x4){0.f, 0.f, 0.f, 0.f};

  // stage slot for k-half js: 3 gload16/thread (A unit0, A unit1, B).
  auto stage = [&](int js) {
    char* db = smem + (js % 3) * 24576;
    long ko = (long)js * 32;
#pragma unroll
    for (int p = 0; p < 2; ++p)
      gload16(Apk + sA + ko + (long)p * 128 * 512, db + p * 8192 + wb1k);
    gload16(Bp + sB + ko, db + 16384 + wb1k);
  };

  // --- Prologue: slots 0,1 in flight (6 loads/thread).
  stage(0);
  stage(1);

#pragma unroll
  for (int j = 0; j < 16; ++j) {
    if (j <= 14)
      asm volatile("s_waitcnt vmcnt(3)" ::: "memory");
    else
      asm volatile("s_waitcnt vmcnt(0)" ::: "memory");
    SBAR();
    if (j <= 13) stage(j + 2);  // writes slot (j-1)%3: readers passed barrier

    const char* sb = smem + (j % 3) * 24576;
    half8 bv[4], av[4];
#pragma unroll
    for (int nf = 0; nf < 4; ++nf)
      bv[nf] = *reinterpret_cast<const half8*>(sb + offB[nf]);
#pragma unroll
    for (int mf = 0; mf < 4; ++mf)
      av[mf] = *reinterpret_cast<const half8*>(sb + offA[mf]);
    __builtin_amdgcn_s_setprio(1);
#pragma unroll
    for (int mf = 0; mf < 4; ++mf)
#pragma unroll
      for (int nf = 0; nf < 4; ++nf)
        acc[mf][nf] = __builtin_amdgcn_mfma_f32_16x16x32_f16(
            av[mf], bv[nf], acc[mf][nf], 0, 0, 0);
    __builtin_amdgcn_s_setprio(0);
  }

  // --- Epilogue: n-frag == gate (0=f,1=i,2=o,3=c); C/D: col=lane&15,
  // row=(lane>>4)*4+reg.
  int col = (bn * 2 + wcn) * 16 + l15;  // logical column in [0,256)
  float vbf = bf_[col], vbi = bi_[col], vbo = bo_[col], vbc = bc_[col];
#pragma unroll
  for (int mf = 0; mf < 4; ++mf) {
#pragma unroll
    for (int r = 0; r < 4; ++r) {
      long row = (long)(bm * 256 + wr * 64 + mf * 16 + lg * 4 + r);
      float zf = acc[mf][0][r] + vbf;
      float zi = acc[mf][1][r] + vbi;
      float zo = acc[mf][2][r] + vbo;
      float zg = acc[mf][3][r] + vbc;
      float fg = fast_sigmoid(zf);
      float ig = fast_sigmoid(zi);
      float og = fast_sigmoid(zo);
      float gg = fast_tanh(zg);
      float cv = cin[row * 256 + col];
      float cn = cv * fg + gg * ig;
      float hn = og * fast_tanh(cn);
      out[row * 256 + col] = cn;
      out[BHSZ + row * 256 + col] = hn;
    }
  }
}

// ---------------------------------------------------------------------------
extern "C" void kernel_launch(void* const* d_in, const int* in_sizes, int n_in,
                              void* d_out, int out_size, void* d_ws, size_t ws_size,
                              hipStream_t stream) {
  const float* x  = (const float*)d_in[0];
  const float* c  = (const float*)d_in[1];
  const float* h  = (const float*)d_in[2];
  const float* Wi = (const float*)d_in[3];
  const float* Ui = (const float*)d_in[4];
  const float* bi = (const float*)d_in[5];
  const float* Wf = (const float*)d_in[6];
  const float* Uf = (const float*)d_in[7];
  const float* bf = (const float*)d_in[8];
  const float* Wc = (const float*)d_in[9];
  const float* Uc = (const float*)d_in[10];
  const float* bc = (const float*)d_in[11];
  const float* Wo = (const float*)d_in[12];
  const float* Uo = (const float*)d_in[13];
  const float* bo = (const float*)d_in[14];

  _Float16* Apk = (_Float16*)d_ws;                                    // 64 MB
  _Float16* Bp  = (_Float16*)((char*)d_ws + (size_t)65536 * 512 * 2); // 1 MB

  pack_a<<<16384, 256, 0, stream>>>(x, h, Apk);
  pack_b<<<2048, 256, 0, stream>>>(Wf, Uf, Wi, Ui, Wo, Uo, Wc, Uc, Bp);
  lstm_gemm<<<2048, 512, 0, stream>>>(Apk, Bp, c, bf, bi, bo, bc,
                                      (float*)d_out);
}